// Round 1
// baseline (109.246 us; speedup 1.0000x reference)
//
#include <hip/hip_runtime.h>

#define B_GRAPHS 64
#define MPG 32
#define TPG 8192
#define NM 2048
#define NT 524288
#define NL 65536
#define H 64
#define DT 18
#define DM 8

// ---------------------------------------------------------------------------
// K1: machine encoder. 64 blocks x 256 threads; wave W handles machines
// W*8 .. W*8+7, lane j owns output dim j. Writes mh[2048][64] and
// mh_contrib[m][j] = mh[m] @ lg_w1[128:192]. Zeroes the padding row 2048.
// ---------------------------------------------------------------------------
__global__ __launch_bounds__(256) void k_machines(
    const float* __restrict__ xm,
    const float* __restrict__ m_ln_g, const float* __restrict__ m_ln_b,
    const float* __restrict__ m_w1, const float* __restrict__ m_b1,
    const float* __restrict__ m_w2, const float* __restrict__ m_b2,
    const float* __restrict__ lg_w1,
    float* __restrict__ mh,          // [2048][64]
    float* __restrict__ mh_contrib)  // [2049][64]
{
    int tid = threadIdx.x;
    int lane = tid & 63;
    int wv = tid >> 6;
    __shared__ float s_h[4][64];
    __shared__ float s_m[4][64];

    if (blockIdx.x == 0 && tid < 64) mh_contrib[(long)NM * H + tid] = 0.0f;

    float w1r[DM];
#pragma unroll
    for (int i = 0; i < DM; i++) w1r[i] = m_w1[i * H + lane];
    float w2r[H];
#pragma unroll
    for (int i = 0; i < H; i++) w2r[i] = m_w2[i * H + lane];
    float Cr[H];
#pragma unroll
    for (int i = 0; i < H; i++) Cr[i] = lg_w1[(2 * H + i) * H + lane];
    float b1 = m_b1[lane], b2 = m_b2[lane];
    float g0[DM], bb[DM];
#pragma unroll
    for (int i = 0; i < DM; i++) { g0[i] = m_ln_g[i]; bb[i] = m_ln_b[i]; }

    int W = blockIdx.x * 4 + wv;
    for (int k = 0; k < 8; k++) {
        int m = W * 8 + k;
        float x[DM];
#pragma unroll
        for (int i = 0; i < DM; i++) x[i] = xm[m * DM + i];
        float mu = 0.0f;
#pragma unroll
        for (int i = 0; i < DM; i++) mu += x[i];
        mu *= (1.0f / DM);
        float var = 0.0f;
#pragma unroll
        for (int i = 0; i < DM; i++) { float d = x[i] - mu; var += d * d; }
        var *= (1.0f / DM);
        float rs = rsqrtf(var + 1e-5f);
        float h = b1;
#pragma unroll
        for (int i = 0; i < DM; i++) {
            float xn = (x[i] - mu) * rs * g0[i] + bb[i];
            h = fmaf(xn, w1r[i], h);
        }
        h = fmaxf(h, 0.0f);
        __syncthreads();            // WAR on s_h from previous iteration
        s_h[wv][lane] = h;
        __syncthreads();            // RAW
        float o = b2;
#pragma unroll
        for (int i = 0; i < H; i++) o = fmaf(s_h[wv][i], w2r[i], o);
        __syncthreads();            // WAR on s_m from previous iteration
        s_m[wv][lane] = o;
        __syncthreads();            // RAW
        float c = 0.0f;
#pragma unroll
        for (int i = 0; i < H; i++) c = fmaf(s_m[wv][i], Cr[i], c);
        mh[(long)m * H + lane] = o;
        mh_contrib[(long)m * H + lane] = c;
    }
}

// ---------------------------------------------------------------------------
// K0: fold weights.  64 blocks x 64 threads.  block i, thread j:
//   W_comb[i][j]  = sum_k t_w2[i][k]  * lg_w1[k][j]        (rows 0..63 = A)
//   W2comb[i][j]  = sum_k lg_w2[i][k] * o_w1[k][j]
// block 0 also: biasA[j] = lg_b1[j] + t_b2 @ A ; bias2[j] = o_b1[j] + lg_b2 @ o_w1
// ---------------------------------------------------------------------------
__global__ __launch_bounds__(64) void k_fold(
    const float* __restrict__ t_w2, const float* __restrict__ lg_w1,
    const float* __restrict__ lg_w2, const float* __restrict__ o_w1,
    const float* __restrict__ t_b2, const float* __restrict__ lg_b1,
    const float* __restrict__ lg_b2, const float* __restrict__ o_b1,
    float* __restrict__ W_comb, float* __restrict__ W2comb,
    float* __restrict__ biasA, float* __restrict__ bias2)
{
    int i = blockIdx.x, j = threadIdx.x;
    float a = 0.0f, b = 0.0f;
    for (int k = 0; k < H; k++) {
        a = fmaf(t_w2[i * H + k],  lg_w1[k * H + j], a);
        b = fmaf(lg_w2[i * H + k], o_w1[k * H + j], b);
    }
    W_comb[i * H + j] = a;
    W2comb[i * H + j] = b;
    if (i == 0) {
        float ba = lg_b1[j], b2v = o_b1[j];
        for (int k = 0; k < H; k++) {
            ba  = fmaf(t_b2[k],  lg_w1[k * H + j], ba);
            b2v = fmaf(lg_b2[k], o_w1[k * H + j], b2v);
        }
        biasA[j] = ba;
        bias2[j] = b2v;
    }
}

// ---------------------------------------------------------------------------
// K2: task relu-sum.  512 blocks x 256 threads; block b owns tasks
// [b*1024, b*1024+1024) (all in one graph: 8 blocks per graph).
// Tile 256 tasks into LDS, LayerNorm in place, then wave wv processes rows
// wv*64..+63 with lane j owning output dim j (w1 column j in registers).
// Emits partial sums of relu(LN(x) @ t_w1 + t_b1) per block (deterministic,
// no atomics).
// ---------------------------------------------------------------------------
__global__ __launch_bounds__(256) void k_tasks(
    const float* __restrict__ xt,
    const float* __restrict__ t_ln_g, const float* __restrict__ t_ln_b,
    const float* __restrict__ t_w1, const float* __restrict__ t_b1,
    float* __restrict__ t_sum_partial,   // [512][64]
    float* __restrict__ t_cnt_partial)   // [512]
{
    __shared__ float s_xn[256][20];      // stride 20 keeps 16B alignment
    __shared__ float s_red[4][64];
    __shared__ float s_g[DT], s_b[DT];
    int tid = threadIdx.x, lane = tid & 63, wv = tid >> 6;
    if (tid < DT) { s_g[tid] = t_ln_g[tid]; s_b[tid] = t_ln_b[tid]; }

    float w1r[DT];
#pragma unroll
    for (int i = 0; i < DT; i++) w1r[i] = t_w1[i * H + lane];
    float b1 = t_b1[lane];
    float acc = 0.0f;
    long base = (long)blockIdx.x * 1024;
    __syncthreads();

    for (int tile = 0; tile < 4; tile++) {
        const float* src = xt + (base + tile * 256) * DT;
#pragma unroll
        for (int k = 0; k < DT; k++) {          // coalesced stage: 4608 floats
            int idx = tid + k * 256;
            int r = idx / DT, c = idx - r * DT;
            s_xn[r][c] = src[idx];
        }
        __syncthreads();
        // LayerNorm of row `tid`
        float xv[DT];
        float mu = 0.0f;
#pragma unroll
        for (int i = 0; i < DT; i++) { xv[i] = s_xn[tid][i]; mu += xv[i]; }
        mu *= (1.0f / DT);
        float var = 0.0f;
#pragma unroll
        for (int i = 0; i < DT; i++) { float d = xv[i] - mu; var += d * d; }
        var *= (1.0f / DT);
        float rs = rsqrtf(var + 1e-5f);
#pragma unroll
        for (int i = 0; i < DT; i++) s_xn[tid][i] = (xv[i] - mu) * rs * s_g[i] + s_b[i];
        __syncthreads();
        // compute: lane j accumulates relu(h1_j) over this wave's 64 rows
        for (int t = 0; t < 64; t++) {
            int row = (wv << 6) + t;
            float xr[DT];
#pragma unroll
            for (int i = 0; i < DT; i++) xr[i] = s_xn[row][i];
            float h = b1;
#pragma unroll
            for (int i = 0; i < DT; i++) h = fmaf(xr[i], w1r[i], h);
            acc += fmaxf(h, 0.0f);
        }
        __syncthreads();    // before next tile overwrites s_xn
    }
    s_red[wv][lane] = acc;
    __syncthreads();
    if (tid < 64) {
        float s = s_red[0][tid] + s_red[1][tid] + s_red[2][tid] + s_red[3][tid];
        t_sum_partial[blockIdx.x * 64 + tid] = s;
    }
    if (tid == 0) t_cnt_partial[blockIdx.x] = 1024.0f;
}

// ---------------------------------------------------------------------------
// K3: per-graph aggregation.  64 blocks (one per graph) x 64 threads.
// t_mean -> aggr MLP -> aggr_contrib[g] = aggr@lg_w1[64:128] + biasA.
// Also machine mean (from mh), machine counts and exclusive cumsum (cum).
// ---------------------------------------------------------------------------
__global__ __launch_bounds__(64) void k_graph(
    const float* __restrict__ t_sum_partial, const float* __restrict__ t_cnt_partial,
    const float* __restrict__ mh, const int* __restrict__ mbatch,
    const float* __restrict__ t_w2, const float* __restrict__ t_b2,
    const float* __restrict__ a_w1, const float* __restrict__ a_b1,
    const float* __restrict__ a_w2, const float* __restrict__ a_b2,
    const float* __restrict__ lg_w1, const float* __restrict__ biasA,
    float* __restrict__ aggr_contrib, int* __restrict__ cum)
{
    int g = blockIdx.x, j = threadIdx.x;
    __shared__ float rs_[64], tm[64], mm[64], ah[64], ag[64];
    __shared__ float s_tcnt;
    __shared__ int s_lt[64], s_eq[64];

    float s = 0.0f;
    for (int p = 0; p < 8; p++) s += t_sum_partial[(g * 8 + p) * 64 + j];
    rs_[j] = s;
    if (j == 0) {
        float c = 0.0f;
        for (int p = 0; p < 8; p++) c += t_cnt_partial[g * 8 + p];
        s_tcnt = c;
    }
    // machine counts (honest scan of x_machines_batch)
    int clt = 0, ceq = 0;
    for (int k = 0; k < 32; k++) {
        int bt = mbatch[j * 32 + k];
        clt += (bt < g) ? 1 : 0;
        ceq += (bt == g) ? 1 : 0;
    }
    s_lt[j] = clt; s_eq[j] = ceq;
    float msum = 0.0f;
    for (int k = 0; k < MPG; k++) msum += mh[(long)(g * MPG + k) * H + j];
    __syncthreads();

    int cum_g = 0, mcnt = 0;
    for (int k = 0; k < 64; k++) { cum_g += s_lt[k]; mcnt += s_eq[k]; }
    if (j == 0) cum[g] = cum_g;

    float tcnt = s_tcnt;
    float dot = 0.0f;
    for (int i = 0; i < H; i++) dot = fmaf(rs_[i], t_w2[i * H + j], dot);
    tm[j] = (dot + tcnt * t_b2[j]) / fmaxf(tcnt, 1.0f);
    mm[j] = msum / fmaxf((float)mcnt, 1.0f);
    __syncthreads();

    float h = a_b1[j];
    for (int i = 0; i < H; i++) h = fmaf(tm[i], a_w1[i * H + j], h);
    for (int i = 0; i < H; i++) h = fmaf(mm[i], a_w1[(H + i) * H + j], h);
    ah[j] = fmaxf(h, 0.0f);
    __syncthreads();

    float o = a_b2[j];
    for (int i = 0; i < H; i++) o = fmaf(ah[i], a_w2[i * H + j], o);
    ag[j] = o;
    __syncthreads();

    float c = biasA[j];
    for (int i = 0; i < H; i++) c = fmaf(ag[i], lg_w1[(H + i) * H + j], c);
    aggr_contrib[g * H + j] = c;
}

// ---------------------------------------------------------------------------
// K4: per-label fused head.  256 blocks x 256 threads, one label per thread.
//   a1 = relu(LN(x_t) @ t_w1 + t_b1)
//   p1 = a1 @ W_comb + aggr_contrib[g] + mh_contrib[m]      (pre-activation)
//   p2 = relu(p1) @ W2comb + bias2
//   out = relu(p2) @ o_w2 + o_b2
// ---------------------------------------------------------------------------
__global__ __launch_bounds__(256) void k_labels(
    const float* __restrict__ xt, const int* __restrict__ tbatch,
    const int* __restrict__ lidx,
    const float* __restrict__ t_ln_g, const float* __restrict__ t_ln_b,
    const float* __restrict__ t_w1, const float* __restrict__ t_b1,
    const float* __restrict__ W_comb, const float* __restrict__ W2comb,
    const float* __restrict__ bias2,
    const float* __restrict__ o_w2, const float* __restrict__ o_b2,
    const float* __restrict__ aggr_contrib, const float* __restrict__ mh_contrib,
    const int* __restrict__ cum,
    float* __restrict__ out)
{
    __shared__ float s_w1[DT * H];
    __shared__ float s_Wc[H * H];
    __shared__ float s_W2[H * H];
    __shared__ float s_b1[H], s_bias2[H], s_ow2[H];
    __shared__ float s_g[DT], s_lb[DT];
    __shared__ float s_ob2;
    int tid = threadIdx.x;
    for (int i = tid; i < DT * H; i += 256) s_w1[i] = t_w1[i];
    for (int i = tid; i < H * H; i += 256) { s_Wc[i] = W_comb[i]; s_W2[i] = W2comb[i]; }
    if (tid < H) { s_b1[tid] = t_b1[tid]; s_bias2[tid] = bias2[tid]; s_ow2[tid] = o_w2[tid]; }
    if (tid < DT) { s_g[tid] = t_ln_g[tid]; s_lb[tid] = t_ln_b[tid]; }
    if (tid == 0) s_ob2 = o_b2[0];
    __syncthreads();

    int l = blockIdx.x * 256 + tid;
    int t = lidx[l];
    const float* xr = xt + (long)t * DT;
    float x[DT];
#pragma unroll
    for (int i = 0; i < DT; i++) x[i] = xr[i];
    int g = tbatch[t];
    int assign = (int)x[0];
    int m = (assign < 0) ? NM : (assign + cum[g]);
    const float4* acp = (const float4*)(aggr_contrib + g * H);
    const float4* mcp = (const float4*)(mh_contrib + (long)m * H);

    // LayerNorm
    float mu = 0.0f;
#pragma unroll
    for (int i = 0; i < DT; i++) mu += x[i];
    mu *= (1.0f / DT);
    float var = 0.0f;
#pragma unroll
    for (int i = 0; i < DT; i++) { float d = x[i] - mu; var += d * d; }
    var *= (1.0f / DT);
    float rsv = rsqrtf(var + 1e-5f);
    float xn[DT];
#pragma unroll
    for (int i = 0; i < DT; i++) xn[i] = (x[i] - mu) * rsv * s_g[i] + s_lb[i];

    // layer 1: a1 = relu(xn @ t_w1 + t_b1)
    float a1[H];
#pragma unroll
    for (int j = 0; j < H; j++) a1[j] = s_b1[j];
    for (int i = 0; i < DT; i++) {
        float xv = xn[i];
        const float4* wr = (const float4*)(s_w1 + i * H);
#pragma unroll
        for (int q = 0; q < 16; q++) {
            float4 w = wr[q];
            a1[4 * q + 0] = fmaf(xv, w.x, a1[4 * q + 0]);
            a1[4 * q + 1] = fmaf(xv, w.y, a1[4 * q + 1]);
            a1[4 * q + 2] = fmaf(xv, w.z, a1[4 * q + 2]);
            a1[4 * q + 3] = fmaf(xv, w.w, a1[4 * q + 3]);
        }
    }
#pragma unroll
    for (int j = 0; j < H; j++) a1[j] = fmaxf(a1[j], 0.0f);

    // p1 = a1 @ W_comb + aggr_contrib[g] + mh_contrib[m]
    float p1[H];
#pragma unroll
    for (int q = 0; q < 16; q++) {
        float4 a = acp[q], b = mcp[q];
        p1[4 * q + 0] = a.x + b.x;
        p1[4 * q + 1] = a.y + b.y;
        p1[4 * q + 2] = a.z + b.z;
        p1[4 * q + 3] = a.w + b.w;
    }
    for (int i = 0; i < H; i++) {
        float hv = a1[i];
        const float4* wr = (const float4*)(s_Wc + i * H);
#pragma unroll
        for (int q = 0; q < 16; q++) {
            float4 w = wr[q];
            p1[4 * q + 0] = fmaf(hv, w.x, p1[4 * q + 0]);
            p1[4 * q + 1] = fmaf(hv, w.y, p1[4 * q + 1]);
            p1[4 * q + 2] = fmaf(hv, w.z, p1[4 * q + 2]);
            p1[4 * q + 3] = fmaf(hv, w.w, p1[4 * q + 3]);
        }
    }

    // p2 = relu(p1) @ W2comb + bias2
    float hid[H];
#pragma unroll
    for (int j = 0; j < H; j++) hid[j] = fmaxf(p1[j], 0.0f);
    float p2[H];
#pragma unroll
    for (int j = 0; j < H; j++) p2[j] = s_bias2[j];
    for (int i = 0; i < H; i++) {
        float hv = hid[i];
        const float4* wr = (const float4*)(s_W2 + i * H);
#pragma unroll
        for (int q = 0; q < 16; q++) {
            float4 w = wr[q];
            p2[4 * q + 0] = fmaf(hv, w.x, p2[4 * q + 0]);
            p2[4 * q + 1] = fmaf(hv, w.y, p2[4 * q + 1]);
            p2[4 * q + 2] = fmaf(hv, w.z, p2[4 * q + 2]);
            p2[4 * q + 3] = fmaf(hv, w.w, p2[4 * q + 3]);
        }
    }

    // out = relu(p2) @ o_w2 + o_b2
    float r0 = 0.0f, r1 = 0.0f, r2 = 0.0f, r3 = 0.0f;
#pragma unroll
    for (int j = 0; j < H; j += 4) {
        r0 = fmaf(fmaxf(p2[j + 0], 0.0f), s_ow2[j + 0], r0);
        r1 = fmaf(fmaxf(p2[j + 1], 0.0f), s_ow2[j + 1], r1);
        r2 = fmaf(fmaxf(p2[j + 2], 0.0f), s_ow2[j + 2], r2);
        r3 = fmaf(fmaxf(p2[j + 3], 0.0f), s_ow2[j + 3], r3);
    }
    out[l] = s_ob2 + ((r0 + r1) + (r2 + r3));
}

// ---------------------------------------------------------------------------
extern "C" void kernel_launch(void* const* d_in, const int* in_sizes, int n_in,
                              void* d_out, int out_size, void* d_ws, size_t ws_size,
                              hipStream_t stream)
{
    (void)n_in; (void)out_size; (void)ws_size;
    const float* x_tasks         = (const float*)d_in[0];
    const float* x_machines      = (const float*)d_in[1];
    const int*   x_tasks_batch   = (const int*)d_in[2];
    const int*   x_machines_batch= (const int*)d_in[3];
    const int*   task_label_idx  = (const int*)d_in[4];
    const float* t_ln_g = (const float*)d_in[5];
    const float* t_ln_b = (const float*)d_in[6];
    const float *m_ln_g, *m_ln_b, *t_w1, *t_b1, *t_w2, *t_b2;
    if (in_sizes[7] == DM) {
        // setup_inputs() dict order: t_ln, m_ln, t_w1, t_b1, t_w2, t_b2, ...
        m_ln_g = (const float*)d_in[7];  m_ln_b = (const float*)d_in[8];
        t_w1   = (const float*)d_in[9];  t_b1   = (const float*)d_in[10];
        t_w2   = (const float*)d_in[11]; t_b2   = (const float*)d_in[12];
    } else {
        // PNAMES order fallback: t_ln, t_w1, t_b1, t_w2, t_b2, m_ln, ...
        t_w1   = (const float*)d_in[7];  t_b1   = (const float*)d_in[8];
        t_w2   = (const float*)d_in[9];  t_b2   = (const float*)d_in[10];
        m_ln_g = (const float*)d_in[11]; m_ln_b = (const float*)d_in[12];
    }
    const float* m_w1 = (const float*)d_in[13]; const float* m_b1 = (const float*)d_in[14];
    const float* m_w2 = (const float*)d_in[15]; const float* m_b2 = (const float*)d_in[16];
    const float* a_w1 = (const float*)d_in[17]; const float* a_b1 = (const float*)d_in[18];
    const float* a_w2 = (const float*)d_in[19]; const float* a_b2 = (const float*)d_in[20];
    const float* lg_w1= (const float*)d_in[21]; const float* lg_b1= (const float*)d_in[22];
    const float* lg_w2= (const float*)d_in[23]; const float* lg_b2= (const float*)d_in[24];
    const float* o_w1 = (const float*)d_in[25]; const float* o_b1 = (const float*)d_in[26];
    const float* o_w2 = (const float*)d_in[27]; const float* o_b2 = (const float*)d_in[28];

    float* ws = (float*)d_ws;
    float* mh_contrib    = ws;                  // 2049*64 = 131136
    float* mh_arr        = ws + 131136;         // 2048*64 = 131072
    float* t_sum_partial = ws + 262208;         // 512*64  = 32768
    float* t_cnt_partial = ws + 294976;         // 512
    float* W_comb        = ws + 295488;         // 4096
    float* W2comb        = ws + 299584;         // 4096
    float* biasA         = ws + 303680;         // 64
    float* bias2         = ws + 303744;         // 64
    float* aggr_contrib  = ws + 303808;         // 4096
    int*   cum           = (int*)(ws + 307904); // 64   (total ~1.18 MB)

    k_machines<<<64, 256, 0, stream>>>(x_machines, m_ln_g, m_ln_b, m_w1, m_b1,
                                       m_w2, m_b2, lg_w1, mh_arr, mh_contrib);
    k_fold<<<64, 64, 0, stream>>>(t_w2, lg_w1, lg_w2, o_w1, t_b2, lg_b1, lg_b2, o_b1,
                                  W_comb, W2comb, biasA, bias2);
    k_tasks<<<512, 256, 0, stream>>>(x_tasks, t_ln_g, t_ln_b, t_w1, t_b1,
                                     t_sum_partial, t_cnt_partial);
    k_graph<<<64, 64, 0, stream>>>(t_sum_partial, t_cnt_partial, mh_arr, x_machines_batch,
                                   t_w2, t_b2, a_w1, a_b1, a_w2, a_b2, lg_w1, biasA,
                                   aggr_contrib, cum);
    k_labels<<<256, 256, 0, stream>>>(x_tasks, x_tasks_batch, task_label_idx,
                                      t_ln_g, t_ln_b, t_w1, t_b1, W_comb, W2comb, bias2,
                                      o_w2, o_b2, aggr_contrib, mh_contrib, cum,
                                      (float*)d_out);
}

// Round 2
// 98.734 us; speedup vs baseline: 1.1065x; 1.1065x over previous
//
#include <hip/hip_runtime.h>

#define B_GRAPHS 64
#define MPG 32
#define TPG 8192
#define NM 2048
#define NT 524288
#define NL 65536
#define H 64
#define DT 18
#define DM 8

// ---------------------------------------------------------------------------
// K1: machine encoder. 64 blocks x 256 threads; wave W handles machines
// W*8 .. W*8+7, lane j owns output dim j. Writes mh[2048][64] and
// mh_contrib[m][j] = mh[m] @ lg_w1[128:192]. Zeroes the padding row 2048.
// ---------------------------------------------------------------------------
__global__ __launch_bounds__(256) void k_machines(
    const float* __restrict__ xm,
    const float* __restrict__ m_ln_g, const float* __restrict__ m_ln_b,
    const float* __restrict__ m_w1, const float* __restrict__ m_b1,
    const float* __restrict__ m_w2, const float* __restrict__ m_b2,
    const float* __restrict__ lg_w1,
    float* __restrict__ mh,          // [2048][64]
    float* __restrict__ mh_contrib)  // [2049][64]
{
    int tid = threadIdx.x;
    int lane = tid & 63;
    int wv = tid >> 6;
    __shared__ float s_h[4][64];
    __shared__ float s_m[4][64];

    if (blockIdx.x == 0 && tid < 64) mh_contrib[(long)NM * H + tid] = 0.0f;

    float w1r[DM];
#pragma unroll
    for (int i = 0; i < DM; i++) w1r[i] = m_w1[i * H + lane];
    float w2r[H];
#pragma unroll
    for (int i = 0; i < H; i++) w2r[i] = m_w2[i * H + lane];
    float Cr[H];
#pragma unroll
    for (int i = 0; i < H; i++) Cr[i] = lg_w1[(2 * H + i) * H + lane];
    float b1 = m_b1[lane], b2 = m_b2[lane];
    float g0[DM], bb[DM];
#pragma unroll
    for (int i = 0; i < DM; i++) { g0[i] = m_ln_g[i]; bb[i] = m_ln_b[i]; }

    int W = blockIdx.x * 4 + wv;
    for (int k = 0; k < 8; k++) {
        int m = W * 8 + k;
        float x[DM];
#pragma unroll
        for (int i = 0; i < DM; i++) x[i] = xm[m * DM + i];
        float mu = 0.0f;
#pragma unroll
        for (int i = 0; i < DM; i++) mu += x[i];
        mu *= (1.0f / DM);
        float var = 0.0f;
#pragma unroll
        for (int i = 0; i < DM; i++) { float d = x[i] - mu; var += d * d; }
        var *= (1.0f / DM);
        float rs = rsqrtf(var + 1e-5f);
        float h = b1;
#pragma unroll
        for (int i = 0; i < DM; i++) {
            float xn = (x[i] - mu) * rs * g0[i] + bb[i];
            h = fmaf(xn, w1r[i], h);
        }
        h = fmaxf(h, 0.0f);
        __syncthreads();            // WAR on s_h from previous iteration
        s_h[wv][lane] = h;
        __syncthreads();            // RAW
        float o = b2;
#pragma unroll
        for (int i = 0; i < H; i++) o = fmaf(s_h[wv][i], w2r[i], o);
        __syncthreads();            // WAR on s_m from previous iteration
        s_m[wv][lane] = o;
        __syncthreads();            // RAW
        float c = 0.0f;
#pragma unroll
        for (int i = 0; i < H; i++) c = fmaf(s_m[wv][i], Cr[i], c);
        mh[(long)m * H + lane] = o;
        mh_contrib[(long)m * H + lane] = c;
    }
}

// ---------------------------------------------------------------------------
// K0: fold weights.  64 blocks x 64 threads.  block i, thread j:
//   W_comb[i][j]  = sum_k t_w2[i][k]  * lg_w1[k][j]
//   W2comb[i][j]  = sum_k lg_w2[i][k] * o_w1[k][j]
// block 0 also: biasA[j] = lg_b1[j] + t_b2 @ A ; bias2[j] = o_b1[j] + lg_b2 @ o_w1
// ---------------------------------------------------------------------------
__global__ __launch_bounds__(64) void k_fold(
    const float* __restrict__ t_w2, const float* __restrict__ lg_w1,
    const float* __restrict__ lg_w2, const float* __restrict__ o_w1,
    const float* __restrict__ t_b2, const float* __restrict__ lg_b1,
    const float* __restrict__ lg_b2, const float* __restrict__ o_b1,
    float* __restrict__ W_comb, float* __restrict__ W2comb,
    float* __restrict__ biasA, float* __restrict__ bias2)
{
    int i = blockIdx.x, j = threadIdx.x;
    float a = 0.0f, b = 0.0f;
    for (int k = 0; k < H; k++) {
        a = fmaf(t_w2[i * H + k],  lg_w1[k * H + j], a);
        b = fmaf(lg_w2[i * H + k], o_w1[k * H + j], b);
    }
    W_comb[i * H + j] = a;
    W2comb[i * H + j] = b;
    if (i == 0) {
        float ba = lg_b1[j], b2v = o_b1[j];
        for (int k = 0; k < H; k++) {
            ba  = fmaf(t_b2[k],  lg_w1[k * H + j], ba);
            b2v = fmaf(lg_b2[k], o_w1[k * H + j], b2v);
        }
        biasA[j] = ba;
        bias2[j] = b2v;
    }
}

// ---------------------------------------------------------------------------
// K2: task relu-sum.  512 blocks x 256 threads; block b owns tasks
// [b*1024, b*1024+1024).  Emits partial sums of relu(LN(x) @ t_w1 + t_b1).
// ---------------------------------------------------------------------------
__global__ __launch_bounds__(256) void k_tasks(
    const float* __restrict__ xt,
    const float* __restrict__ t_ln_g, const float* __restrict__ t_ln_b,
    const float* __restrict__ t_w1, const float* __restrict__ t_b1,
    float* __restrict__ t_sum_partial,   // [512][64]
    float* __restrict__ t_cnt_partial)   // [512]
{
    __shared__ float s_xn[256][20];      // stride 20 keeps 16B alignment
    __shared__ float s_red[4][64];
    __shared__ float s_g[DT], s_b[DT];
    int tid = threadIdx.x, lane = tid & 63, wv = tid >> 6;
    if (tid < DT) { s_g[tid] = t_ln_g[tid]; s_b[tid] = t_ln_b[tid]; }

    float w1r[DT];
#pragma unroll
    for (int i = 0; i < DT; i++) w1r[i] = t_w1[i * H + lane];
    float b1 = t_b1[lane];
    float acc = 0.0f;
    long base = (long)blockIdx.x * 1024;
    __syncthreads();

    for (int tile = 0; tile < 4; tile++) {
        const float* src = xt + (base + tile * 256) * DT;
#pragma unroll
        for (int k = 0; k < DT; k++) {          // coalesced stage: 4608 floats
            int idx = tid + k * 256;
            int r = idx / DT, c = idx - r * DT;
            s_xn[r][c] = src[idx];
        }
        __syncthreads();
        float xv[DT];
        float mu = 0.0f;
#pragma unroll
        for (int i = 0; i < DT; i++) { xv[i] = s_xn[tid][i]; mu += xv[i]; }
        mu *= (1.0f / DT);
        float var = 0.0f;
#pragma unroll
        for (int i = 0; i < DT; i++) { float d = xv[i] - mu; var += d * d; }
        var *= (1.0f / DT);
        float rs = rsqrtf(var + 1e-5f);
#pragma unroll
        for (int i = 0; i < DT; i++) s_xn[tid][i] = (xv[i] - mu) * rs * s_g[i] + s_b[i];
        __syncthreads();
        for (int t = 0; t < 64; t++) {
            int row = (wv << 6) + t;
            float xr[DT];
#pragma unroll
            for (int i = 0; i < DT; i++) xr[i] = s_xn[row][i];
            float h = b1;
#pragma unroll
            for (int i = 0; i < DT; i++) h = fmaf(xr[i], w1r[i], h);
            acc += fmaxf(h, 0.0f);
        }
        __syncthreads();    // before next tile overwrites s_xn
    }
    s_red[wv][lane] = acc;
    __syncthreads();
    if (tid < 64) {
        float s = s_red[0][tid] + s_red[1][tid] + s_red[2][tid] + s_red[3][tid];
        t_sum_partial[blockIdx.x * 64 + tid] = s;
    }
    if (tid == 0) t_cnt_partial[blockIdx.x] = 1024.0f;
}

// ---------------------------------------------------------------------------
// K3: per-graph aggregation.  64 blocks (one per graph) x 64 threads.
// ---------------------------------------------------------------------------
__global__ __launch_bounds__(64) void k_graph(
    const float* __restrict__ t_sum_partial, const float* __restrict__ t_cnt_partial,
    const float* __restrict__ mh, const int* __restrict__ mbatch,
    const float* __restrict__ t_w2, const float* __restrict__ t_b2,
    const float* __restrict__ a_w1, const float* __restrict__ a_b1,
    const float* __restrict__ a_w2, const float* __restrict__ a_b2,
    const float* __restrict__ lg_w1, const float* __restrict__ biasA,
    float* __restrict__ aggr_contrib, int* __restrict__ cum)
{
    int g = blockIdx.x, j = threadIdx.x;
    __shared__ float rs_[64], tm[64], mm[64], ah[64], ag[64];
    __shared__ float s_tcnt;
    __shared__ int s_lt[64], s_eq[64];

    float s = 0.0f;
    for (int p = 0; p < 8; p++) s += t_sum_partial[(g * 8 + p) * 64 + j];
    rs_[j] = s;
    if (j == 0) {
        float c = 0.0f;
        for (int p = 0; p < 8; p++) c += t_cnt_partial[g * 8 + p];
        s_tcnt = c;
    }
    int clt = 0, ceq = 0;
    for (int k = 0; k < 32; k++) {
        int bt = mbatch[j * 32 + k];
        clt += (bt < g) ? 1 : 0;
        ceq += (bt == g) ? 1 : 0;
    }
    s_lt[j] = clt; s_eq[j] = ceq;
    float msum = 0.0f;
    for (int k = 0; k < MPG; k++) msum += mh[(long)(g * MPG + k) * H + j];
    __syncthreads();

    int cum_g = 0, mcnt = 0;
    for (int k = 0; k < 64; k++) { cum_g += s_lt[k]; mcnt += s_eq[k]; }
    if (j == 0) cum[g] = cum_g;

    float tcnt = s_tcnt;
    float dot = 0.0f;
    for (int i = 0; i < H; i++) dot = fmaf(rs_[i], t_w2[i * H + j], dot);
    tm[j] = (dot + tcnt * t_b2[j]) / fmaxf(tcnt, 1.0f);
    mm[j] = msum / fmaxf((float)mcnt, 1.0f);
    __syncthreads();

    float h = a_b1[j];
    for (int i = 0; i < H; i++) h = fmaf(tm[i], a_w1[i * H + j], h);
    for (int i = 0; i < H; i++) h = fmaf(mm[i], a_w1[(H + i) * H + j], h);
    ah[j] = fmaxf(h, 0.0f);
    __syncthreads();

    float o = a_b2[j];
    for (int i = 0; i < H; i++) o = fmaf(ah[i], a_w2[i * H + j], o);
    ag[j] = o;
    __syncthreads();

    float c = biasA[j];
    for (int i = 0; i < H; i++) c = fmaf(ag[i], lg_w1[(H + i) * H + j], c);
    aggr_contrib[g * H + j] = c;
}

// ---------------------------------------------------------------------------
// K4 v2: per-label fused head, NO per-thread runtime-indexed register arrays.
// Activations live in LDS columns s_act[i][tid] (thread-private column -> no
// barriers, conflict-free).  Accumulators acc[64] stay in registers with all
// j-indices compile-time (float4-unrolled).  Runtime i-loops read activations
// from LDS (dynamic indexing legal) and weights via uniform (broadcast)
// ds_read_b128.  Zero scratch by construction.
// ---------------------------------------------------------------------------
__global__ __launch_bounds__(256) void k_labels2(
    const float* __restrict__ xt, const int* __restrict__ tbatch,
    const int* __restrict__ lidx,
    const float* __restrict__ t_ln_g, const float* __restrict__ t_ln_b,
    const float* __restrict__ t_w1, const float* __restrict__ t_b1,
    const float* __restrict__ W_comb, const float* __restrict__ W2comb,
    const float* __restrict__ bias2,
    const float* __restrict__ o_w2, const float* __restrict__ o_b2,
    const float* __restrict__ aggr_contrib, const float* __restrict__ mh_contrib,
    const int* __restrict__ cum,
    float* __restrict__ out)
{
    __shared__ float s_act[H * 256];     // 64 KB: activation columns
    __shared__ float s_w1[DT * H];       // 4.5 KB
    __shared__ float s_Wc[H * H];        // 16 KB
    __shared__ float s_W2[H * H];        // 16 KB
    __shared__ float s_b1[H], s_bias2[H], s_ow2[H];
    __shared__ float s_g[DT], s_lb[DT];
    __shared__ float s_ob2;
    int tid = threadIdx.x;
    for (int i = tid; i < DT * H; i += 256) s_w1[i] = t_w1[i];
    for (int i = tid; i < H * H; i += 256) { s_Wc[i] = W_comb[i]; s_W2[i] = W2comb[i]; }
    if (tid < H) { s_b1[tid] = t_b1[tid]; s_bias2[tid] = bias2[tid]; s_ow2[tid] = o_w2[tid]; }
    if (tid < DT) { s_g[tid] = t_ln_g[tid]; s_lb[tid] = t_ln_b[tid]; }
    if (tid == 0) s_ob2 = o_b2[0];
    __syncthreads();

    int l = blockIdx.x * 256 + tid;
    int t = lidx[l];
    const float* xr = xt + (long)t * DT;
    float x[DT];
#pragma unroll
    for (int i = 0; i < DT; i++) x[i] = xr[i];
    int g = tbatch[t];
    int assign = (int)x[0];
    int m = (assign < 0) ? NM : (assign + cum[g]);

    // LayerNorm (all compile-time indexed -> registers)
    float mu = 0.0f;
#pragma unroll
    for (int i = 0; i < DT; i++) mu += x[i];
    mu *= (1.0f / DT);
    float var = 0.0f;
#pragma unroll
    for (int i = 0; i < DT; i++) { float d = x[i] - mu; var += d * d; }
    var *= (1.0f / DT);
    float rsv = rsqrtf(var + 1e-5f);
#pragma unroll
    for (int i = 0; i < DT; i++)
        s_act[i * 256 + tid] = (x[i] - mu) * rsv * s_g[i] + s_lb[i];

    float acc[H];

    // layer 1: acc = xn @ t_w1 + t_b1   (runtime i, weights broadcast b128)
    {
        const float4* bp = (const float4*)s_b1;
#pragma unroll
        for (int q = 0; q < 16; q++) {
            float4 b = bp[q];
            acc[4 * q + 0] = b.x; acc[4 * q + 1] = b.y;
            acc[4 * q + 2] = b.z; acc[4 * q + 3] = b.w;
        }
        for (int i = 0; i < DT; i++) {
            float av = s_act[i * 256 + tid];
            const float4* wr = (const float4*)(s_w1 + i * H);
#pragma unroll
            for (int q = 0; q < 16; q++) {
                float4 w = wr[q];
                acc[4 * q + 0] = fmaf(av, w.x, acc[4 * q + 0]);
                acc[4 * q + 1] = fmaf(av, w.y, acc[4 * q + 1]);
                acc[4 * q + 2] = fmaf(av, w.z, acc[4 * q + 2]);
                acc[4 * q + 3] = fmaf(av, w.w, acc[4 * q + 3]);
            }
        }
    }
    // a1 = relu -> LDS columns (xn rows dead by now; same thread only)
#pragma unroll
    for (int q = 0; q < H; q++) s_act[q * 256 + tid] = fmaxf(acc[q], 0.0f);

    // p1 = a1 @ W_comb + aggr_contrib[g] + mh_contrib[m]
    {
        const float4* acp = (const float4*)(aggr_contrib + g * H);
        const float4* mcp = (const float4*)(mh_contrib + (long)m * H);
#pragma unroll
        for (int q = 0; q < 16; q++) {
            float4 a = acp[q], b = mcp[q];
            acc[4 * q + 0] = a.x + b.x;
            acc[4 * q + 1] = a.y + b.y;
            acc[4 * q + 2] = a.z + b.z;
            acc[4 * q + 3] = a.w + b.w;
        }
        for (int i = 0; i < H; i++) {
            float av = s_act[i * 256 + tid];
            const float4* wr = (const float4*)(s_Wc + i * H);
#pragma unroll
            for (int q = 0; q < 16; q++) {
                float4 w = wr[q];
                acc[4 * q + 0] = fmaf(av, w.x, acc[4 * q + 0]);
                acc[4 * q + 1] = fmaf(av, w.y, acc[4 * q + 1]);
                acc[4 * q + 2] = fmaf(av, w.z, acc[4 * q + 2]);
                acc[4 * q + 3] = fmaf(av, w.w, acc[4 * q + 3]);
            }
        }
    }
    // hid = relu(p1) -> LDS columns (a1 rows dead)
#pragma unroll
    for (int q = 0; q < H; q++) s_act[q * 256 + tid] = fmaxf(acc[q], 0.0f);

    // p2 = hid @ W2comb + bias2
    {
        const float4* bp = (const float4*)s_bias2;
#pragma unroll
        for (int q = 0; q < 16; q++) {
            float4 b = bp[q];
            acc[4 * q + 0] = b.x; acc[4 * q + 1] = b.y;
            acc[4 * q + 2] = b.z; acc[4 * q + 3] = b.w;
        }
        for (int i = 0; i < H; i++) {
            float av = s_act[i * 256 + tid];
            const float4* wr = (const float4*)(s_W2 + i * H);
#pragma unroll
            for (int q = 0; q < 16; q++) {
                float4 w = wr[q];
                acc[4 * q + 0] = fmaf(av, w.x, acc[4 * q + 0]);
                acc[4 * q + 1] = fmaf(av, w.y, acc[4 * q + 1]);
                acc[4 * q + 2] = fmaf(av, w.z, acc[4 * q + 2]);
                acc[4 * q + 3] = fmaf(av, w.w, acc[4 * q + 3]);
            }
        }
    }

    // out = relu(p2) @ o_w2 + o_b2   (compile-time indexed)
    float r0 = 0.0f, r1 = 0.0f, r2 = 0.0f, r3 = 0.0f;
    {
        const float4* wp = (const float4*)s_ow2;
#pragma unroll
        for (int q = 0; q < 16; q++) {
            float4 w = wp[q];
            r0 = fmaf(fmaxf(acc[4 * q + 0], 0.0f), w.x, r0);
            r1 = fmaf(fmaxf(acc[4 * q + 1], 0.0f), w.y, r1);
            r2 = fmaf(fmaxf(acc[4 * q + 2], 0.0f), w.z, r2);
            r3 = fmaf(fmaxf(acc[4 * q + 3], 0.0f), w.w, r3);
        }
    }
    out[l] = s_ob2 + ((r0 + r1) + (r2 + r3));
}

// ---------------------------------------------------------------------------
extern "C" void kernel_launch(void* const* d_in, const int* in_sizes, int n_in,
                              void* d_out, int out_size, void* d_ws, size_t ws_size,
                              hipStream_t stream)
{
    (void)n_in; (void)out_size; (void)ws_size;
    const float* x_tasks         = (const float*)d_in[0];
    const float* x_machines      = (const float*)d_in[1];
    const int*   x_tasks_batch   = (const int*)d_in[2];
    const int*   x_machines_batch= (const int*)d_in[3];
    const int*   task_label_idx  = (const int*)d_in[4];
    const float* t_ln_g = (const float*)d_in[5];
    const float* t_ln_b = (const float*)d_in[6];
    const float *m_ln_g, *m_ln_b, *t_w1, *t_b1, *t_w2, *t_b2;
    if (in_sizes[7] == DM) {
        m_ln_g = (const float*)d_in[7];  m_ln_b = (const float*)d_in[8];
        t_w1   = (const float*)d_in[9];  t_b1   = (const float*)d_in[10];
        t_w2   = (const float*)d_in[11]; t_b2   = (const float*)d_in[12];
    } else {
        t_w1   = (const float*)d_in[7];  t_b1   = (const float*)d_in[8];
        t_w2   = (const float*)d_in[9];  t_b2   = (const float*)d_in[10];
        m_ln_g = (const float*)d_in[11]; m_ln_b = (const float*)d_in[12];
    }
    const float* m_w1 = (const float*)d_in[13]; const float* m_b1 = (const float*)d_in[14];
    const float* m_w2 = (const float*)d_in[15]; const float* m_b2 = (const float*)d_in[16];
    const float* a_w1 = (const float*)d_in[17]; const float* a_b1 = (const float*)d_in[18];
    const float* a_w2 = (const float*)d_in[19]; const float* a_b2 = (const float*)d_in[20];
    const float* lg_w1= (const float*)d_in[21]; const float* lg_b1= (const float*)d_in[22];
    const float* lg_w2= (const float*)d_in[23]; const float* lg_b2= (const float*)d_in[24];
    const float* o_w1 = (const float*)d_in[25]; const float* o_b1 = (const float*)d_in[26];
    const float* o_w2 = (const float*)d_in[27]; const float* o_b2 = (const float*)d_in[28];

    float* ws = (float*)d_ws;
    float* mh_contrib    = ws;                  // 2049*64 = 131136
    float* mh_arr        = ws + 131136;         // 2048*64 = 131072
    float* t_sum_partial = ws + 262208;         // 512*64  = 32768
    float* t_cnt_partial = ws + 294976;         // 512
    float* W_comb        = ws + 295488;         // 4096
    float* W2comb        = ws + 299584;         // 4096
    float* biasA         = ws + 303680;         // 64
    float* bias2         = ws + 303744;         // 64
    float* aggr_contrib  = ws + 303808;         // 4096
    int*   cum           = (int*)(ws + 307904); // 64

    k_machines<<<64, 256, 0, stream>>>(x_machines, m_ln_g, m_ln_b, m_w1, m_b1,
                                       m_w2, m_b2, lg_w1, mh_arr, mh_contrib);
    k_fold<<<64, 64, 0, stream>>>(t_w2, lg_w1, lg_w2, o_w1, t_b2, lg_b1, lg_b2, o_b1,
                                  W_comb, W2comb, biasA, bias2);
    k_tasks<<<512, 256, 0, stream>>>(x_tasks, t_ln_g, t_ln_b, t_w1, t_b1,
                                     t_sum_partial, t_cnt_partial);
    k_graph<<<64, 64, 0, stream>>>(t_sum_partial, t_cnt_partial, mh_arr, x_machines_batch,
                                   t_w2, t_b2, a_w1, a_b1, a_w2, a_b2, lg_w1, biasA,
                                   aggr_contrib, cum);
    k_labels2<<<256, 256, 0, stream>>>(x_tasks, x_tasks_batch, task_label_idx,
                                       t_ln_g, t_ln_b, t_w1, t_b1, W_comb, W2comb, bias2,
                                       o_w2, o_b2, aggr_contrib, mh_contrib, cum,
                                       (float*)d_out);
}

// Round 3
// 71.843 us; speedup vs baseline: 1.5206x; 1.3743x over previous
//
#include <hip/hip_runtime.h>

#define B_GRAPHS 64
#define MPG 32
#define TPG 8192
#define NM 2048
#define NT 524288
#define NL 65536
#define H 64
#define DT 18
#define DM 8

// ---------------------------------------------------------------------------
// K_A: merged independent work.
//   blocks [0,512)   : tasks relu-sum partials   (256 thr)
//   blocks [512,576) : machine encoder + contrib (256 thr)
//   blocks [576,640) : weight folding            (64 active thr)
// ---------------------------------------------------------------------------
__global__ __launch_bounds__(256) void k_front(
    const float* __restrict__ xt,
    const float* __restrict__ t_ln_g, const float* __restrict__ t_ln_b,
    const float* __restrict__ t_w1, const float* __restrict__ t_b1,
    const float* __restrict__ xm,
    const float* __restrict__ m_ln_g, const float* __restrict__ m_ln_b,
    const float* __restrict__ m_w1, const float* __restrict__ m_b1,
    const float* __restrict__ m_w2, const float* __restrict__ m_b2,
    const float* __restrict__ lg_w1,
    const float* __restrict__ t_w2, const float* __restrict__ lg_w2,
    const float* __restrict__ o_w1, const float* __restrict__ t_b2,
    const float* __restrict__ lg_b1, const float* __restrict__ lg_b2,
    const float* __restrict__ o_b1,
    float* __restrict__ t_sum_partial,   // [512][64]
    float* __restrict__ t_cnt_partial,   // [512]
    float* __restrict__ mh,              // [2048][64]
    float* __restrict__ mh_contrib,      // [2049][64]
    float* __restrict__ W_comb, float* __restrict__ W2comb,
    float* __restrict__ biasA, float* __restrict__ bias2)
{
    __shared__ float s_xn[256][20];      // tasks: rows 16B-aligned
    __shared__ float s_red[4][64];
    __shared__ float s_h[4][64];         // machines
    __shared__ float s_m[4][64];

    int tid = threadIdx.x, lane = tid & 63, wv = tid >> 6;
    int bid = blockIdx.x;

    if (bid < 512) {
        // ---------------- tasks part ----------------
        float lg[DT], lb[DT], w1r[DT];
#pragma unroll
        for (int i = 0; i < DT; i++) { lg[i] = t_ln_g[i]; lb[i] = t_ln_b[i]; }
#pragma unroll
        for (int i = 0; i < DT; i++) w1r[i] = t_w1[i * H + lane];
        float b1 = t_b1[lane];
        float acc = 0.0f;
        long base = (long)bid * 1024 * DT;

        for (int tile = 0; tile < 4; tile++) {
            const float4* src4 = (const float4*)(xt + base + (long)tile * 256 * DT);
            for (int q = tid; q < 1152; q += 256) {
                float4 v = src4[q];
                int e = 4 * q;
                int r = e / 18, c = e - r * 18;
                s_xn[r][c] = v.x;
                int c1 = c + 1, r1 = r; if (c1 == 18) { c1 = 0; r1++; }
                s_xn[r1][c1] = v.y;
                int c2 = c1 + 1, r2 = r1; if (c2 == 18) { c2 = 0; r2++; }
                s_xn[r2][c2] = v.z;
                int c3 = c2 + 1, r3 = r2; if (c3 == 18) { c3 = 0; r3++; }
                s_xn[r3][c3] = v.w;
            }
            __syncthreads();
            // LayerNorm of row `tid` (vector LDS access)
            {
                const float4* rp = (const float4*)(&s_xn[tid][0]);
                float4 A = rp[0], Bv = rp[1], C = rp[2], D = rp[3];
                float e16 = s_xn[tid][16], e17 = s_xn[tid][17];
                float xv[DT] = {A.x,A.y,A.z,A.w, Bv.x,Bv.y,Bv.z,Bv.w,
                                C.x,C.y,C.z,C.w, D.x,D.y,D.z,D.w, e16,e17};
                float mu = 0.0f;
#pragma unroll
                for (int i = 0; i < DT; i++) mu += xv[i];
                mu *= (1.0f / DT);
                float var = 0.0f;
#pragma unroll
                for (int i = 0; i < DT; i++) { float d = xv[i] - mu; var += d * d; }
                var *= (1.0f / DT);
                float rs = rsqrtf(var + 1e-5f);
                float xn[DT];
#pragma unroll
                for (int i = 0; i < DT; i++) xn[i] = (xv[i] - mu) * rs * lg[i] + lb[i];
                float4* wp = (float4*)(&s_xn[tid][0]);
                wp[0] = make_float4(xn[0], xn[1], xn[2], xn[3]);
                wp[1] = make_float4(xn[4], xn[5], xn[6], xn[7]);
                wp[2] = make_float4(xn[8], xn[9], xn[10], xn[11]);
                wp[3] = make_float4(xn[12], xn[13], xn[14], xn[15]);
                s_xn[tid][16] = xn[16]; s_xn[tid][17] = xn[17];
            }
            __syncthreads();
            // compute: wave wv over its 64 rows, broadcast b128 reads
            for (int t = 0; t < 64; t++) {
                int row = (wv << 6) + t;
                const float4* rp = (const float4*)(&s_xn[row][0]);
                float4 A = rp[0], Bv = rp[1], C = rp[2], D = rp[3];
                float e16 = s_xn[row][16], e17 = s_xn[row][17];
                float h = b1;
                h = fmaf(A.x, w1r[0], h);  h = fmaf(A.y, w1r[1], h);
                h = fmaf(A.z, w1r[2], h);  h = fmaf(A.w, w1r[3], h);
                h = fmaf(Bv.x, w1r[4], h); h = fmaf(Bv.y, w1r[5], h);
                h = fmaf(Bv.z, w1r[6], h); h = fmaf(Bv.w, w1r[7], h);
                h = fmaf(C.x, w1r[8], h);  h = fmaf(C.y, w1r[9], h);
                h = fmaf(C.z, w1r[10], h); h = fmaf(C.w, w1r[11], h);
                h = fmaf(D.x, w1r[12], h); h = fmaf(D.y, w1r[13], h);
                h = fmaf(D.z, w1r[14], h); h = fmaf(D.w, w1r[15], h);
                h = fmaf(e16, w1r[16], h); h = fmaf(e17, w1r[17], h);
                acc += fmaxf(h, 0.0f);
            }
            __syncthreads();
        }
        s_red[wv][lane] = acc;
        __syncthreads();
        if (tid < 64) {
            float s = s_red[0][tid] + s_red[1][tid] + s_red[2][tid] + s_red[3][tid];
            t_sum_partial[bid * 64 + tid] = s;
        }
        if (tid == 0) t_cnt_partial[bid] = 1024.0f;

    } else if (bid < 576) {
        // ---------------- machines part ----------------
        int mbid = bid - 512;
        if (mbid == 0 && tid < 64) mh_contrib[(long)NM * H + tid] = 0.0f;

        float w1r[DM];
#pragma unroll
        for (int i = 0; i < DM; i++) w1r[i] = m_w1[i * H + lane];
        float w2r[H];
#pragma unroll
        for (int i = 0; i < H; i++) w2r[i] = m_w2[i * H + lane];
        float Cr[H];
#pragma unroll
        for (int i = 0; i < H; i++) Cr[i] = lg_w1[(2 * H + i) * H + lane];
        float b1 = m_b1[lane], b2 = m_b2[lane];
        float g0[DM], bb[DM];
#pragma unroll
        for (int i = 0; i < DM; i++) { g0[i] = m_ln_g[i]; bb[i] = m_ln_b[i]; }

        int W = mbid * 4 + wv;
        for (int k = 0; k < 8; k++) {
            int m = W * 8 + k;
            float x[DM];
#pragma unroll
            for (int i = 0; i < DM; i++) x[i] = xm[m * DM + i];
            float mu = 0.0f;
#pragma unroll
            for (int i = 0; i < DM; i++) mu += x[i];
            mu *= (1.0f / DM);
            float var = 0.0f;
#pragma unroll
            for (int i = 0; i < DM; i++) { float d = x[i] - mu; var += d * d; }
            var *= (1.0f / DM);
            float rs = rsqrtf(var + 1e-5f);
            float h = b1;
#pragma unroll
            for (int i = 0; i < DM; i++) {
                float xn = (x[i] - mu) * rs * g0[i] + bb[i];
                h = fmaf(xn, w1r[i], h);
            }
            h = fmaxf(h, 0.0f);
            __syncthreads();
            s_h[wv][lane] = h;
            __syncthreads();
            float o = b2;
#pragma unroll
            for (int i = 0; i < H; i++) o = fmaf(s_h[wv][i], w2r[i], o);
            __syncthreads();
            s_m[wv][lane] = o;
            __syncthreads();
            float c = 0.0f;
#pragma unroll
            for (int i = 0; i < H; i++) c = fmaf(s_m[wv][i], Cr[i], c);
            mh[(long)m * H + lane] = o;
            mh_contrib[(long)m * H + lane] = c;
        }
    } else {
        // ---------------- fold part ----------------
        int i = bid - 576, j = tid;
        if (j < 64) {
            float a = 0.0f, b = 0.0f;
            for (int k = 0; k < H; k++) {
                a = fmaf(t_w2[i * H + k],  lg_w1[k * H + j], a);
                b = fmaf(lg_w2[i * H + k], o_w1[k * H + j], b);
            }
            W_comb[i * H + j] = a;
            W2comb[i * H + j] = b;
            if (i == 0) {
                float ba = lg_b1[j], b2v = o_b1[j];
                for (int k = 0; k < H; k++) {
                    ba  = fmaf(t_b2[k],  lg_w1[k * H + j], ba);
                    b2v = fmaf(lg_b2[k], o_w1[k * H + j], b2v);
                }
                biasA[j] = ba;
                bias2[j] = b2v;
            }
        }
    }
}

// ---------------------------------------------------------------------------
// K3: per-graph aggregation.  64 blocks (one per graph) x 64 threads.
// ---------------------------------------------------------------------------
__global__ __launch_bounds__(64) void k_graph(
    const float* __restrict__ t_sum_partial, const float* __restrict__ t_cnt_partial,
    const float* __restrict__ mh, const int* __restrict__ mbatch,
    const float* __restrict__ t_w2, const float* __restrict__ t_b2,
    const float* __restrict__ a_w1, const float* __restrict__ a_b1,
    const float* __restrict__ a_w2, const float* __restrict__ a_b2,
    const float* __restrict__ lg_w1, const float* __restrict__ biasA,
    float* __restrict__ aggr_contrib, int* __restrict__ cum)
{
    int g = blockIdx.x, j = threadIdx.x;
    __shared__ float rs_[64], tm[64], mm[64], ah[64], ag[64];
    __shared__ float s_tcnt;
    __shared__ int s_lt[64], s_eq[64];

    float s = 0.0f;
    for (int p = 0; p < 8; p++) s += t_sum_partial[(g * 8 + p) * 64 + j];
    rs_[j] = s;
    if (j == 0) {
        float c = 0.0f;
        for (int p = 0; p < 8; p++) c += t_cnt_partial[g * 8 + p];
        s_tcnt = c;
    }
    int clt = 0, ceq = 0;
    for (int k = 0; k < 32; k++) {
        int bt = mbatch[j * 32 + k];
        clt += (bt < g) ? 1 : 0;
        ceq += (bt == g) ? 1 : 0;
    }
    s_lt[j] = clt; s_eq[j] = ceq;
    float msum = 0.0f;
    for (int k = 0; k < MPG; k++) msum += mh[(long)(g * MPG + k) * H + j];
    __syncthreads();

    int cum_g = 0, mcnt = 0;
    for (int k = 0; k < 64; k++) { cum_g += s_lt[k]; mcnt += s_eq[k]; }
    if (j == 0) cum[g] = cum_g;

    float tcnt = s_tcnt;
    float dot = 0.0f;
    for (int i = 0; i < H; i++) dot = fmaf(rs_[i], t_w2[i * H + j], dot);
    tm[j] = (dot + tcnt * t_b2[j]) / fmaxf(tcnt, 1.0f);
    mm[j] = msum / fmaxf((float)mcnt, 1.0f);
    __syncthreads();

    float h = a_b1[j];
    for (int i = 0; i < H; i++) h = fmaf(tm[i], a_w1[i * H + j], h);
    for (int i = 0; i < H; i++) h = fmaf(mm[i], a_w1[(H + i) * H + j], h);
    ah[j] = fmaxf(h, 0.0f);
    __syncthreads();

    float o = a_b2[j];
    for (int i = 0; i < H; i++) o = fmaf(ah[i], a_w2[i * H + j], o);
    ag[j] = o;
    __syncthreads();

    float c = biasA[j];
    for (int i = 0; i < H; i++) c = fmaf(ag[i], lg_w1[(H + i) * H + j], c);
    aggr_contrib[g * H + j] = c;
}

// ---------------------------------------------------------------------------
// K4 v3: per-label fused head, wave-split output dims for occupancy.
// 512 blocks x 512 threads; block handles 128 labels. Wave w (0..7) owns
// output dims w*8..w*8+7; lane handles labels {lane, lane+64}. Activations
// in LDS [dim][label] (stride-1 across lanes); weights broadcast b128.
// acc registers all compile-time indexed -> zero scratch. 71KB LDS ->
// 2 blocks/CU = 16 waves/CU.
// ---------------------------------------------------------------------------
__global__ __launch_bounds__(512) void k_labels3(
    const float* __restrict__ xt, const int* __restrict__ tbatch,
    const int* __restrict__ lidx,
    const float* __restrict__ t_ln_g, const float* __restrict__ t_ln_b,
    const float* __restrict__ t_w1, const float* __restrict__ t_b1,
    const float* __restrict__ W_comb, const float* __restrict__ W2comb,
    const float* __restrict__ bias2,
    const float* __restrict__ o_w2, const float* __restrict__ o_b2,
    const float* __restrict__ aggr_contrib, const float* __restrict__ mh_contrib,
    const int* __restrict__ cum,
    float* __restrict__ out)
{
    __shared__ float s_act[H * 128];      // 32 KB [dim][label]
    __shared__ float s_w1[DT * H];        // 4.5 KB
    __shared__ float s_Wc[H * H];         // 16 KB
    __shared__ float s_W2[H * H];         // 16 KB
    __shared__ float s_b1v[H], s_b2v[H], s_ow2[H];
    __shared__ float s_lng[DT], s_lnb[DT];
    __shared__ int   s_gi[128], s_mi[128], s_t[128];
    __shared__ float s_ob2v;

    int tid = threadIdx.x, lane = tid & 63, w = tid >> 6;   // w in 0..7
    int wb = w * 8;

    for (int i = tid; i < DT * H; i += 512) s_w1[i] = t_w1[i];
    for (int i = tid; i < H * H; i += 512) { s_Wc[i] = W_comb[i]; s_W2[i] = W2comb[i]; }
    if (tid < H) { s_b1v[tid] = t_b1[tid]; s_b2v[tid] = bias2[tid]; s_ow2[tid] = o_w2[tid]; }
    if (tid < DT) { s_lng[tid] = t_ln_g[tid]; s_lnb[tid] = t_ln_b[tid]; }
    if (tid == 0) s_ob2v = o_b2[0];
    if (tid < 128) {
        int t = lidx[blockIdx.x * 128 + tid];
        s_t[tid] = t;
        int g = tbatch[t];
        int assign = (int)xt[(long)t * DT];
        s_gi[tid] = g;
        s_mi[tid] = (assign < 0) ? NM : (assign + cum[g]);
    }
    __syncthreads();

    // feature gather: 2 threads per label, 9 floats each -> [dim][label]
    if (tid < 256) {
        int r = tid >> 1, hh = tid & 1;
        const float* src = xt + (long)s_t[r] * DT + hh * 9;
#pragma unroll
        for (int j = 0; j < 9; j++) s_act[(hh * 9 + j) * 128 + r] = src[j];
    }
    __syncthreads();

    // LayerNorm per label (tid<128), columns are thread-private
    if (tid < 128) {
        float xv[DT];
#pragma unroll
        for (int i = 0; i < DT; i++) xv[i] = s_act[i * 128 + tid];
        float mu = 0.0f;
#pragma unroll
        for (int i = 0; i < DT; i++) mu += xv[i];
        mu *= (1.0f / DT);
        float var = 0.0f;
#pragma unroll
        for (int i = 0; i < DT; i++) { float d = xv[i] - mu; var += d * d; }
        var *= (1.0f / DT);
        float rs = rsqrtf(var + 1e-5f);
#pragma unroll
        for (int i = 0; i < DT; i++)
            s_act[i * 128 + tid] = (xv[i] - mu) * rs * s_lng[i] + s_lnb[i];
    }
    __syncthreads();

    float acc0[8], acc1[8];

    // ---- L1: a1 = relu(xn @ t_w1 + b1), dims wb..wb+7 ----
#pragma unroll
    for (int k = 0; k < 8; k++) { acc0[k] = s_b1v[wb + k]; acc1[k] = acc0[k]; }
    for (int i = 0; i < DT; i++) {
        float av0 = s_act[i * 128 + lane];
        float av1 = s_act[i * 128 + 64 + lane];
        const float4* wp = (const float4*)(s_w1 + i * H + wb);
        float4 wA = wp[0], wB = wp[1];
        acc0[0] = fmaf(av0, wA.x, acc0[0]); acc1[0] = fmaf(av1, wA.x, acc1[0]);
        acc0[1] = fmaf(av0, wA.y, acc0[1]); acc1[1] = fmaf(av1, wA.y, acc1[1]);
        acc0[2] = fmaf(av0, wA.z, acc0[2]); acc1[2] = fmaf(av1, wA.z, acc1[2]);
        acc0[3] = fmaf(av0, wA.w, acc0[3]); acc1[3] = fmaf(av1, wA.w, acc1[3]);
        acc0[4] = fmaf(av0, wB.x, acc0[4]); acc1[4] = fmaf(av1, wB.x, acc1[4]);
        acc0[5] = fmaf(av0, wB.y, acc0[5]); acc1[5] = fmaf(av1, wB.y, acc1[5]);
        acc0[6] = fmaf(av0, wB.z, acc0[6]); acc1[6] = fmaf(av1, wB.z, acc1[6]);
        acc0[7] = fmaf(av0, wB.w, acc0[7]); acc1[7] = fmaf(av1, wB.w, acc1[7]);
    }
    __syncthreads();                       // all xn reads done
#pragma unroll
    for (int k = 0; k < 8; k++) {
        s_act[(wb + k) * 128 + lane]      = fmaxf(acc0[k], 0.0f);
        s_act[(wb + k) * 128 + 64 + lane] = fmaxf(acc1[k], 0.0f);
    }
    __syncthreads();

    // ---- L2: p1 = a1 @ W_comb + aggr_contrib[g] + mh_contrib[m] ----
    {
        int g0 = s_gi[lane],      m0 = s_mi[lane];
        int g1 = s_gi[64 + lane], m1 = s_mi[64 + lane];
        const float4* a0p = (const float4*)(aggr_contrib + g0 * H + wb);
        const float4* m0p = (const float4*)(mh_contrib + (long)m0 * H + wb);
        const float4* a1p = (const float4*)(aggr_contrib + g1 * H + wb);
        const float4* m1p = (const float4*)(mh_contrib + (long)m1 * H + wb);
        float4 aA = a0p[0], aB = a0p[1], mA = m0p[0], mB = m0p[1];
        float4 cA = a1p[0], cB = a1p[1], nA = m1p[0], nB = m1p[1];
        acc0[0] = aA.x + mA.x; acc0[1] = aA.y + mA.y; acc0[2] = aA.z + mA.z; acc0[3] = aA.w + mA.w;
        acc0[4] = aB.x + mB.x; acc0[5] = aB.y + mB.y; acc0[6] = aB.z + mB.z; acc0[7] = aB.w + mB.w;
        acc1[0] = cA.x + nA.x; acc1[1] = cA.y + nA.y; acc1[2] = cA.z + nA.z; acc1[3] = cA.w + nA.w;
        acc1[4] = cB.x + nB.x; acc1[5] = cB.y + nB.y; acc1[6] = cB.z + nB.z; acc1[7] = cB.w + nB.w;
    }
    for (int i = 0; i < H; i++) {
        float av0 = s_act[i * 128 + lane];
        float av1 = s_act[i * 128 + 64 + lane];
        const float4* wp = (const float4*)(s_Wc + i * H + wb);
        float4 wA = wp[0], wB = wp[1];
        acc0[0] = fmaf(av0, wA.x, acc0[0]); acc1[0] = fmaf(av1, wA.x, acc1[0]);
        acc0[1] = fmaf(av0, wA.y, acc0[1]); acc1[1] = fmaf(av1, wA.y, acc1[1]);
        acc0[2] = fmaf(av0, wA.z, acc0[2]); acc1[2] = fmaf(av1, wA.z, acc1[2]);
        acc0[3] = fmaf(av0, wA.w, acc0[3]); acc1[3] = fmaf(av1, wA.w, acc1[3]);
        acc0[4] = fmaf(av0, wB.x, acc0[4]); acc1[4] = fmaf(av1, wB.x, acc1[4]);
        acc0[5] = fmaf(av0, wB.y, acc0[5]); acc1[5] = fmaf(av1, wB.y, acc1[5]);
        acc0[6] = fmaf(av0, wB.z, acc0[6]); acc1[6] = fmaf(av1, wB.z, acc1[6]);
        acc0[7] = fmaf(av0, wB.w, acc0[7]); acc1[7] = fmaf(av1, wB.w, acc1[7]);
    }
    __syncthreads();                       // all a1 reads done
#pragma unroll
    for (int k = 0; k < 8; k++) {
        s_act[(wb + k) * 128 + lane]      = fmaxf(acc0[k], 0.0f);
        s_act[(wb + k) * 128 + 64 + lane] = fmaxf(acc1[k], 0.0f);
    }
    __syncthreads();

    // ---- L3: p2 = hid @ W2comb + bias2 ----
#pragma unroll
    for (int k = 0; k < 8; k++) { acc0[k] = s_b2v[wb + k]; acc1[k] = acc0[k]; }
    for (int i = 0; i < H; i++) {
        float av0 = s_act[i * 128 + lane];
        float av1 = s_act[i * 128 + 64 + lane];
        const float4* wp = (const float4*)(s_W2 + i * H + wb);
        float4 wA = wp[0], wB = wp[1];
        acc0[0] = fmaf(av0, wA.x, acc0[0]); acc1[0] = fmaf(av1, wA.x, acc1[0]);
        acc0[1] = fmaf(av0, wA.y, acc0[1]); acc1[1] = fmaf(av1, wA.y, acc1[1]);
        acc0[2] = fmaf(av0, wA.z, acc0[2]); acc1[2] = fmaf(av1, wA.z, acc1[2]);
        acc0[3] = fmaf(av0, wA.w, acc0[3]); acc1[3] = fmaf(av1, wA.w, acc1[3]);
        acc0[4] = fmaf(av0, wB.x, acc0[4]); acc1[4] = fmaf(av1, wB.x, acc1[4]);
        acc0[5] = fmaf(av0, wB.y, acc0[5]); acc1[5] = fmaf(av1, wB.y, acc1[5]);
        acc0[6] = fmaf(av0, wB.z, acc0[6]); acc1[6] = fmaf(av1, wB.z, acc1[6]);
        acc0[7] = fmaf(av0, wB.w, acc0[7]); acc1[7] = fmaf(av1, wB.w, acc1[7]);
    }

    // ---- final: partial dot with o_w2, reduce across 8 waves via LDS ----
    float r0 = 0.0f, r1 = 0.0f;
#pragma unroll
    for (int k = 0; k < 8; k++) {
        float wv2 = s_ow2[wb + k];
        r0 = fmaf(fmaxf(acc0[k], 0.0f), wv2, r0);
        r1 = fmaf(fmaxf(acc1[k], 0.0f), wv2, r1);
    }
    __syncthreads();                       // all hid reads done; reuse s_act rows 0..7
    s_act[w * 128 + lane]      = r0;
    s_act[w * 128 + 64 + lane] = r1;
    __syncthreads();
    if (tid < 128) {
        float s = s_ob2v;
#pragma unroll
        for (int q = 0; q < 8; q++) s += s_act[q * 128 + tid];
        out[blockIdx.x * 128 + tid] = s;
    }
}

// ---------------------------------------------------------------------------
extern "C" void kernel_launch(void* const* d_in, const int* in_sizes, int n_in,
                              void* d_out, int out_size, void* d_ws, size_t ws_size,
                              hipStream_t stream)
{
    (void)n_in; (void)out_size; (void)ws_size;
    const float* x_tasks         = (const float*)d_in[0];
    const float* x_machines      = (const float*)d_in[1];
    const int*   x_tasks_batch   = (const int*)d_in[2];
    const int*   x_machines_batch= (const int*)d_in[3];
    const int*   task_label_idx  = (const int*)d_in[4];
    const float* t_ln_g = (const float*)d_in[5];
    const float* t_ln_b = (const float*)d_in[6];
    const float *m_ln_g, *m_ln_b, *t_w1, *t_b1, *t_w2, *t_b2;
    if (in_sizes[7] == DM) {
        m_ln_g = (const float*)d_in[7];  m_ln_b = (const float*)d_in[8];
        t_w1   = (const float*)d_in[9];  t_b1   = (const float*)d_in[10];
        t_w2   = (const float*)d_in[11]; t_b2   = (const float*)d_in[12];
    } else {
        t_w1   = (const float*)d_in[7];  t_b1   = (const float*)d_in[8];
        t_w2   = (const float*)d_in[9];  t_b2   = (const float*)d_in[10];
        m_ln_g = (const float*)d_in[11]; m_ln_b = (const float*)d_in[12];
    }
    const float* m_w1 = (const float*)d_in[13]; const float* m_b1 = (const float*)d_in[14];
    const float* m_w2 = (const float*)d_in[15]; const float* m_b2 = (const float*)d_in[16];
    const float* a_w1 = (const float*)d_in[17]; const float* a_b1 = (const float*)d_in[18];
    const float* a_w2 = (const float*)d_in[19]; const float* a_b2 = (const float*)d_in[20];
    const float* lg_w1= (const float*)d_in[21]; const float* lg_b1= (const float*)d_in[22];
    const float* lg_w2= (const float*)d_in[23]; const float* lg_b2= (const float*)d_in[24];
    const float* o_w1 = (const float*)d_in[25]; const float* o_b1 = (const float*)d_in[26];
    const float* o_w2 = (const float*)d_in[27]; const float* o_b2 = (const float*)d_in[28];

    float* ws = (float*)d_ws;
    float* mh_contrib    = ws;                  // 2049*64 = 131136
    float* mh_arr        = ws + 131136;         // 2048*64 = 131072
    float* t_sum_partial = ws + 262208;         // 512*64  = 32768
    float* t_cnt_partial = ws + 294976;         // 512
    float* W_comb        = ws + 295488;         // 4096
    float* W2comb        = ws + 299584;         // 4096
    float* biasA         = ws + 303680;         // 64
    float* bias2         = ws + 303744;         // 64
    float* aggr_contrib  = ws + 303808;         // 4096
    int*   cum           = (int*)(ws + 307904); // 64

    k_front<<<640, 256, 0, stream>>>(x_tasks, t_ln_g, t_ln_b, t_w1, t_b1,
                                     x_machines, m_ln_g, m_ln_b, m_w1, m_b1, m_w2, m_b2,
                                     lg_w1, t_w2, lg_w2, o_w1, t_b2, lg_b1, lg_b2, o_b1,
                                     t_sum_partial, t_cnt_partial, mh_arr, mh_contrib,
                                     W_comb, W2comb, biasA, bias2);
    k_graph<<<64, 64, 0, stream>>>(t_sum_partial, t_cnt_partial, mh_arr, x_machines_batch,
                                   t_w2, t_b2, a_w1, a_b1, a_w2, a_b2, lg_w1, biasA,
                                   aggr_contrib, cum);
    k_labels3<<<512, 512, 0, stream>>>(x_tasks, x_tasks_batch, task_label_idx,
                                       t_ln_g, t_ln_b, t_w1, t_b1, W_comb, W2comb, bias2,
                                       o_w2, o_b2, aggr_contrib, mh_contrib, cum,
                                       (float*)d_out);
}